// Round 12
// baseline (45.136 us; speedup 1.0000x reference)
//
#include <hip/hip_runtime.h>
#include <stdint.h>

typedef unsigned long long u64;
typedef __attribute__((ext_vector_type(4))) float f32x4;    // MFMA acc / f32 LDS read

#define IN_FEATURES 256
#define UNITS 256
#define TM 16                 // rows per tile (one wave-tile)
#define ROW_BYTES 1024        // 256 f32

// ---- sign helpers ----
// fp8 e4m3fn: +1.0 = 0x38, -1.0 = 0xB8, 0 = 0x00. Exact for {-1,0,1}.
__device__ __forceinline__ uint sgn_fp8(float f) {
    uint u = __float_as_uint(f);
    return ((u << 1) == 0u) ? 0u : (0x38u | ((u >> 24) & 0x80u));
}
__device__ __forceinline__ u64 pack8_fp8(f32x4 lo, f32x4 hi) {
    uint p0 = sgn_fp8(lo[0]) | (sgn_fp8(lo[1]) << 8) | (sgn_fp8(lo[2]) << 16) | (sgn_fp8(lo[3]) << 24);
    uint p1 = sgn_fp8(hi[0]) | (sgn_fp8(hi[1]) << 8) | (sgn_fp8(hi[2]) << 16) | (sgn_fp8(hi[3]) << 24);
    return (u64)p0 | ((u64)p1 << 32);
}

// ---------------------------------------------------------------------------
// Pack kernel (verified R7-R10): w -> sign-fp8 in MFMA B-fragment layout.
// Fragment (ks, ct, lane): col = ct*16 + (lane&15), k = ks*32 + (lane>>4)*8 .. +8
// fragB[(ks*16+ct)*64 + lane] = 8 fp8 bytes, k-ascending.  Total 64 KB.
// ---------------------------------------------------------------------------
__global__ __launch_bounds__(256) void pack_w_frag8(const float* __restrict__ w,
                                                    u64* __restrict__ fragB) {
    __shared__ unsigned char ls[256][20];   // [k][c], padded
    const int ct = blockIdx.x;
    const int t = threadIdx.x;

    const float4* wr = (const float4*)(w + (size_t)t * UNITS + ct * 16);
#pragma unroll
    for (int i = 0; i < 4; ++i) {
        const float4 v = wr[i];
        ls[t][i * 4 + 0] = (unsigned char)sgn_fp8(v.x);
        ls[t][i * 4 + 1] = (unsigned char)sgn_fp8(v.y);
        ls[t][i * 4 + 2] = (unsigned char)sgn_fp8(v.z);
        ls[t][i * 4 + 3] = (unsigned char)sgn_fp8(v.w);
    }
    __syncthreads();

#pragma unroll
    for (int h = 0; h < 2; ++h) {
        const int f = t + h * 256;
        const int ks = f >> 6;
        const int lane = f & 63;
        const int c = lane & 15;
        const int k0 = ks * 32 + (lane >> 4) * 8;
        u64 val = 0;
#pragma unroll
        for (int j = 0; j < 8; ++j) val |= ((u64)ls[k0 + j][c]) << (8 * j);
        fragB[(size_t)(ks * 16 + ct) * 64 + lane] = val;
    }
}

// ---------------------------------------------------------------------------
// Main kernel: ONE WAVE PER BLOCK, ZERO BARRIERS. Each wave is a private
// pipeline over 4 row-tiles of 16 rows x 128 cols:
//   DMA 16 raw-f32 rows into private LDS (global_load_lds, 0 VGPRs held,
//   source-swizzled: chunk ^ (row&7), verified R8-R10) -> vmcnt(0) ->
//   swizzled f32x4 LDS reads + in-reg sign->fp8 -> 64 fp8 MFMA (swapped
//   operands, verified) -> 8 plain f32x4 stores (L2-merging; NT falsified R11).
// 8 independent wave-pipelines/CU (16 KB LDS, ~190 VGPR) decohere naturally:
// reads and writes interleave at the memory controller without convoys.
// Col-split 2x128 caps x L3 re-read amplification at 2x.
// ---------------------------------------------------------------------------
__global__ __launch_bounds__(64) void bdense_wave(const float* __restrict__ x,
                                                  const u64* __restrict__ fragB,
                                                  float* __restrict__ out) {
    __shared__ float buf[TM][256];   // 16 KB, raw f32

    const int lane = threadIdx.x;    // 0..63
    const int bid = blockIdx.x;
    const int cg = bid & 1;          // col-group: cols [cg*128, cg*128+128)
    const int rti = bid >> 1;        // row-tile group 0..1023
    const int ct0 = cg * 8;
    const int colbase = cg * 128;

    // ---- B fragments for 8 col-tiles: 64 u64 = 128 VGPRs (L2-resident) ----
    u64 breg[8][8];
#pragma unroll
    for (int ks = 0; ks < 8; ++ks)
#pragma unroll
        for (int nt = 0; nt < 8; ++nt)
            breg[ks][nt] = fragB[(size_t)(ks * 16 + ct0 + nt) * 64 + lane];

    const int rl = lane & 15;
    const int m = rl & 7;
    const int c2 = (lane >> 4) * 2;
    const int cl4 = (lane >> 4) * 4;

#pragma unroll 1
    for (int j = 0; j < 4; ++j) {
        const long row0 = ((long)rti * 4 + j) * TM;

        // ds_reads of previous tile fully retired before DMA overwrites buf
        asm volatile("s_waitcnt lgkmcnt(0)" ::: "memory");

        // ---- DMA: 16 rows, 1 KB per instruction, zero VGPRs held ----
        const char* xb = (const char*)(x + (size_t)row0 * IN_FEATURES);
#pragma unroll
        for (int r = 0; r < TM; ++r) {
            const char* src = xb + (size_t)r * ROW_BYTES + ((lane ^ (r & 7)) << 4);
            __builtin_amdgcn_global_load_lds(
                (const __attribute__((address_space(1))) void*)(uintptr_t)src,
                (__attribute__((address_space(3))) void*)(uint32_t)(uintptr_t)&buf[r][0],
                16, 0, 0);
        }
        asm volatile("s_waitcnt vmcnt(0)" ::: "memory");
        __builtin_amdgcn_sched_barrier(0);

        // ---- compute: 8 k-steps x 8 col-tiles ----
        f32x4 acc[8];
#pragma unroll
        for (int nt = 0; nt < 8; ++nt) acc[nt] = (f32x4){0.f, 0.f, 0.f, 0.f};

#pragma unroll
        for (int ks = 0; ks < 8; ++ks) {
            const int c0 = ks * 8 + c2;          // 16B-chunk index (even)
            const f32x4 lo = *(const f32x4*)&buf[rl][(c0 ^ m) << 2];
            const f32x4 hi = *(const f32x4*)&buf[rl][((c0 + 1) ^ m) << 2];
            const long a = (long)pack8_fp8(lo, hi);
#pragma unroll
            for (int nt = 0; nt < 8; ++nt)
                acc[nt] = __builtin_amdgcn_mfma_f32_16x16x32_fp8_fp8(
                    (long)breg[ks][nt], a, acc[nt], 0, 0, 0);
        }

        // ---- store: transposed-C, lane holds row rl, 4 consecutive cols ----
        const long rowt = row0 + rl;
#pragma unroll
        for (int nt = 0; nt < 8; ++nt)
            *(f32x4*)(out + rowt * UNITS + colbase + nt * 16 + cl4) = acc[nt];
    }
}

// ---------------------------------------------------------------------------
// Fallback (ws too small): round-2 popcount path, known-correct.
// ---------------------------------------------------------------------------
__global__ __launch_bounds__(256) void pack_w_bits(const float* __restrict__ w,
                                                   u64* __restrict__ wp) {
    const int t = blockIdx.x;
    const int j = threadIdx.x;
    u64 s = 0, z = 0;
#pragma unroll
    for (int b = 0; b < 64; ++b) {
        const float v = w[(4 * b + t) * UNITS + j];
        s |= ((u64)(v < 0.0f)) << b;
        z |= ((u64)(v != 0.0f)) << b;
    }
    wp[j * 4 + t] = s;
    wp[1024 + j * 4 + t] = z;
}

__global__ __launch_bounds__(256) void bdense_pop(const float4* __restrict__ x4,
                                                  const u64* __restrict__ wp,
                                                  float4* __restrict__ out4) {
    const int tid = threadIdx.x;
    const int lane = tid & 63;
    const int wid = tid >> 6;
    const long row0 = (long)blockIdx.x * 32 + (long)wid * 8;

    u64 ws_[4][4], wz_[4][4];
#pragma unroll
    for (int i = 0; i < 4; ++i)
#pragma unroll
        for (int t = 0; t < 4; ++t) {
            ws_[i][t] = wp[(4 * lane + i) * 4 + t];
            wz_[i][t] = wp[1024 + (4 * lane + i) * 4 + t];
        }

#pragma unroll
    for (int r = 0; r < 8; ++r) {
        const float4 v = x4[(row0 + r) * (IN_FEATURES / 4) + lane];
        u64 rs[4], rz[4];
        rs[0] = __ballot(v.x < 0.0f); rz[0] = __ballot(v.x != 0.0f);
        rs[1] = __ballot(v.y < 0.0f); rz[1] = __ballot(v.y != 0.0f);
        rs[2] = __ballot(v.z < 0.0f); rz[2] = __ballot(v.z != 0.0f);
        rs[3] = __ballot(v.w < 0.0f); rz[3] = __ballot(v.w != 0.0f);
        float o[4];
#pragma unroll
        for (int i = 0; i < 4; ++i) {
            int nzc = 0, ngc = 0;
#pragma unroll
            for (int t = 0; t < 4; ++t) {
                const u64 nz = rz[t] & wz_[i][t];
                const u64 d = (rs[t] ^ ws_[i][t]) & nz;
                nzc += __popcll(nz);
                ngc += __popcll(d);
            }
            o[i] = (float)(nzc - 2 * ngc);
        }
        out4[(row0 + r) * (UNITS / 4) + lane] = make_float4(o[0], o[1], o[2], o[3]);
    }
}

extern "C" void kernel_launch(void* const* d_in, const int* in_sizes, int n_in,
                              void* d_out, int out_size, void* d_ws, size_t ws_size,
                              hipStream_t stream) {
    const float* x = (const float*)d_in[0];
    const float* w = (const float*)d_in[1];
    float* out = (float*)d_out;

    const int batch = in_sizes[0] / IN_FEATURES;  // 65536

    if (ws_size >= 65536 && batch % (TM * 4) == 0) {
        u64* fragB = (u64*)d_ws;
        pack_w_frag8<<<16, 256, 0, stream>>>(w, fragB);
        // 2 col-groups x (batch/16/4) row-tile groups, 64 threads each
        bdense_wave<<<(batch / (TM * 4)) * 2, 64, 0, stream>>>(x, fragB, out);
    } else {
        u64* wp = (u64*)d_ws;  // 16 KB
        pack_w_bits<<<4, 256, 0, stream>>>(w, wp);
        bdense_pop<<<batch / 32, 256, 0, stream>>>((const float4*)x, wp, (float4*)out);
    }
}

// Round 13
// 36.486 us; speedup vs baseline: 1.2371x; 1.2371x over previous
//
#include <hip/hip_runtime.h>
#include <stdint.h>

typedef unsigned long long u64;
typedef __attribute__((ext_vector_type(4))) float f32x4;    // MFMA acc

#define IN_FEATURES 256
#define UNITS 256
#define BM 32          // rows per block
#define LDP 264        // LDS row pitch in bytes (256 + 8)

// ---- sign helpers ----
// fp8 e4m3fn: +1.0 = 0x38, -1.0 = 0xB8, 0 = 0x00. Exact for {-1,0,1}.
__device__ __forceinline__ uint sgn_fp8(float f) {
    uint u = __float_as_uint(f);
    return ((u << 1) == 0u) ? 0u : (0x38u | ((u >> 24) & 0x80u));
}
__device__ __forceinline__ uint sgn_fp8_pack4(float4 v) {
    return sgn_fp8(v.x) | (sgn_fp8(v.y) << 8) | (sgn_fp8(v.z) << 16) | (sgn_fp8(v.w) << 24);
}

// ---------------------------------------------------------------------------
// Pack kernel (verified R7-R12): w -> sign-fp8 in MFMA B-fragment layout.
// Fragment (ks, ct, lane): col = ct*16 + (lane&15), k = ks*32 + (lane>>4)*8 .. +8
// fragB[(ks*16+ct)*64 + lane] = 8 fp8 bytes, k-ascending.  Total 64 KB.
// ---------------------------------------------------------------------------
__global__ __launch_bounds__(256) void pack_w_frag8(const float* __restrict__ w,
                                                    u64* __restrict__ fragB) {
    __shared__ unsigned char ls[256][20];   // [k][c], padded
    const int ct = blockIdx.x;
    const int t = threadIdx.x;

    const float4* wr = (const float4*)(w + (size_t)t * UNITS + ct * 16);
#pragma unroll
    for (int i = 0; i < 4; ++i) {
        const float4 v = wr[i];
        ls[t][i * 4 + 0] = (unsigned char)sgn_fp8(v.x);
        ls[t][i * 4 + 1] = (unsigned char)sgn_fp8(v.y);
        ls[t][i * 4 + 2] = (unsigned char)sgn_fp8(v.z);
        ls[t][i * 4 + 3] = (unsigned char)sgn_fp8(v.w);
    }
    __syncthreads();

#pragma unroll
    for (int h = 0; h < 2; ++h) {
        const int f = t + h * 256;
        const int ks = f >> 6;
        const int lane = f & 63;
        const int c = lane & 15;
        const int k0 = ks * 32 + (lane >> 4) * 8;
        u64 val = 0;
#pragma unroll
        for (int j = 0; j < 8; ++j) val |= ((u64)ls[k0 + j][c]) << (8 * j);
        fragB[(size_t)(ks * 16 + ct) * 64 + lane] = val;
    }
}

// ---------------------------------------------------------------------------
// Main kernel = R5's proven structure (stage -> one barrier -> k-loop with
// in-loop L2 B-fragment loads -> store), shrunk for residency:
//   BM 64->32, bf16->fp8: LDS 33.8->8.4 KB, acc 64->32 AGPRs.
//   => ~5 blocks/CU, ~20 waves/CU (vs R5's 4 blocks / 16 waves).
// Components: fp8 staging values (R7), fragB layout (R7), swapped-operand
// MFMA + f32x4 transposed-C stores (R6/R7/R10), plain stores (NT falsified).
// ---------------------------------------------------------------------------
__global__ __launch_bounds__(256) void bdense_v13(const float4* __restrict__ x4,
                                                  const u64* __restrict__ fragB,
                                                  float* __restrict__ out) {
    __shared__ unsigned char xs8[BM][LDP];   // 8448 B

    const int tid = threadIdx.x;
    const int lane = tid & 63;
    const int wid = tid >> 6;
    const long row0 = (long)blockIdx.x * BM;

    // --- stage: 32 rows x 256 k as fp8; wave-instr i writes one full row ---
    // f = i*256 + tid -> r = i*4 + wid, kq = lane  (coalesced float4 loads,
    // consecutive-dword LDS writes: 2-way bank aliasing = free)
#pragma unroll
    for (int i = 0; i < 8; ++i) {
        const int r = i * 4 + wid;
        const float4 v = x4[(row0 + r) * (IN_FEATURES / 4) + lane];
        *(uint*)&xs8[r][lane * 4] = sgn_fp8_pack4(v);
    }
    __syncthreads();

    const int rl = lane & 15;
    const int hi8 = (lane >> 4) * 8;
    const int ct0 = wid * 4;

    f32x4 acc[2][4];
#pragma unroll
    for (int mt = 0; mt < 2; ++mt)
#pragma unroll
        for (int nt = 0; nt < 4; ++nt) acc[mt][nt] = (f32x4){0.f, 0.f, 0.f, 0.f};

#pragma unroll
    for (int ks = 0; ks < 8; ++ks) {
        const int ko = ks * 32 + hi8;
        const u64 a0 = *(const u64*)&xs8[rl][ko];        // ds_read_b64
        const u64 a1 = *(const u64*)&xs8[16 + rl][ko];
        u64 b[4];
#pragma unroll
        for (int nt = 0; nt < 4; ++nt)                   // coalesced 512B/wave, L2
            b[nt] = fragB[(size_t)(ks * 16 + ct0 + nt) * 64 + lane];
#pragma unroll
        for (int nt = 0; nt < 4; ++nt) {
            acc[0][nt] = __builtin_amdgcn_mfma_f32_16x16x32_fp8_fp8(
                (long)b[nt], (long)a0, acc[0][nt], 0, 0, 0);
            acc[1][nt] = __builtin_amdgcn_mfma_f32_16x16x32_fp8_fp8(
                (long)b[nt], (long)a1, acc[1][nt], 0, 0, 0);
        }
    }

    // --- store: transposed-C, lane holds row rl, 4 consecutive cols ---
    const int cl4 = (lane >> 4) * 4;
    const int colbase = wid * 64;
#pragma unroll
    for (int mt = 0; mt < 2; ++mt) {
        const long rowt = row0 + mt * 16 + rl;
#pragma unroll
        for (int nt = 0; nt < 4; ++nt)
            *(f32x4*)(out + rowt * UNITS + colbase + nt * 16 + cl4) = acc[mt][nt];
    }
}

// ---------------------------------------------------------------------------
// Fallback (ws too small): round-2 popcount path, known-correct.
// ---------------------------------------------------------------------------
__global__ __launch_bounds__(256) void pack_w_bits(const float* __restrict__ w,
                                                   u64* __restrict__ wp) {
    const int t = blockIdx.x;
    const int j = threadIdx.x;
    u64 s = 0, z = 0;
#pragma unroll
    for (int b = 0; b < 64; ++b) {
        const float v = w[(4 * b + t) * UNITS + j];
        s |= ((u64)(v < 0.0f)) << b;
        z |= ((u64)(v != 0.0f)) << b;
    }
    wp[j * 4 + t] = s;
    wp[1024 + j * 4 + t] = z;
}

__global__ __launch_bounds__(256) void bdense_pop(const float4* __restrict__ x4,
                                                  const u64* __restrict__ wp,
                                                  float4* __restrict__ out4) {
    const int tid = threadIdx.x;
    const int lane = tid & 63;
    const int wid = tid >> 6;
    const long row0 = (long)blockIdx.x * 32 + (long)wid * 8;

    u64 ws_[4][4], wz_[4][4];
#pragma unroll
    for (int i = 0; i < 4; ++i)
#pragma unroll
        for (int t = 0; t < 4; ++t) {
            ws_[i][t] = wp[(4 * lane + i) * 4 + t];
            wz_[i][t] = wp[1024 + (4 * lane + i) * 4 + t];
        }

#pragma unroll
    for (int r = 0; r < 8; ++r) {
        const float4 v = x4[(row0 + r) * (IN_FEATURES / 4) + lane];
        u64 rs[4], rz[4];
        rs[0] = __ballot(v.x < 0.0f); rz[0] = __ballot(v.x != 0.0f);
        rs[1] = __ballot(v.y < 0.0f); rz[1] = __ballot(v.y != 0.0f);
        rs[2] = __ballot(v.z < 0.0f); rz[2] = __ballot(v.z != 0.0f);
        rs[3] = __ballot(v.w < 0.0f); rz[3] = __ballot(v.w != 0.0f);
        float o[4];
#pragma unroll
        for (int i = 0; i < 4; ++i) {
            int nzc = 0, ngc = 0;
#pragma unroll
            for (int t = 0; t < 4; ++t) {
                const u64 nz = rz[t] & wz_[i][t];
                const u64 d = (rs[t] ^ ws_[i][t]) & nz;
                nzc += __popcll(nz);
                ngc += __popcll(d);
            }
            o[i] = (float)(nzc - 2 * ngc);
        }
        out4[(row0 + r) * (UNITS / 4) + lane] = make_float4(o[0], o[1], o[2], o[3]);
    }
}

extern "C" void kernel_launch(void* const* d_in, const int* in_sizes, int n_in,
                              void* d_out, int out_size, void* d_ws, size_t ws_size,
                              hipStream_t stream) {
    const float* x = (const float*)d_in[0];
    const float* w = (const float*)d_in[1];
    float* out = (float*)d_out;

    const int batch = in_sizes[0] / IN_FEATURES;  // 65536

    if (ws_size >= 65536 && batch % BM == 0) {
        u64* fragB = (u64*)d_ws;
        pack_w_frag8<<<16, 256, 0, stream>>>(w, fragB);
        bdense_v13<<<batch / BM, 256, 0, stream>>>((const float4*)x, fragB, out);
    } else {
        u64* wp = (u64*)d_ws;  // 16 KB
        pack_w_bits<<<4, 256, 0, stream>>>(w, wp);
        bdense_pop<<<batch / 32, 256, 0, stream>>>((const float4*)x, wp, (float4*)out);
    }
}